// Round 3
// baseline (362.168 us; speedup 1.0000x reference)
//
#include <hip/hip_runtime.h>
#include <hip/hip_bf16.h>

// SNN EventProp LIF forward, 2 layers: 784 -> 1024 -> 256, T=100, B=256.
//
// Structure: LIF current I is LINEAR in the matmul results -> all T matmuls
// of a layer collapse into one batched sparse op + per-(b,n) time scan.
// Both matmul inputs are BINARY spikes (x ~5%; layer-1 spikes are rare), so
// each "GEMM" is a sparse gather-ADD of weight rows (fp32-exact, no mults).
//
// Pipeline:
//   transpose W1 -> W1T [784,1024], W2 -> W2T [1024,256]
//   sparse1 : C1[25088,1024] += W1T rows of active x entries (float4 cols)
//   scan1   : S1u8[25344,1024] spikes (t=0 zeroed), float4/uchar4
//   layer2  : ONE wave per batch b; per t: read S1 row (16B/lane), share
//             actives via __ballot, gather W2T rows (L2-hot), scan I/V in
//             registers, write out. No C2, no barriers.
//
// ALPHA=0.8f, BETA=0.95f, 1-BETA=0.05f (exact float32 of the Python consts).

#define ALPHA_F 0.8f
#define BETA_F 0.95f
#define ONE_MINUS_BETA_F 0.05f

// WT[k*N + n] = W[n*K + k].  W: [N,K] row-major.
__global__ __launch_bounds__(256) void transpose_nt(const float* __restrict__ W,
                                                    float* __restrict__ WT,
                                                    int N, int K) {
    __shared__ float tile[32][33];
    const int k0 = blockIdx.x * 32, n0 = blockIdx.y * 32;
    const int tx = threadIdx.x & 31, ty = threadIdx.x >> 5;   // 32 x 8
#pragma unroll
    for (int r = 0; r < 4; ++r) {
        int n = n0 + ty + r * 8, k = k0 + tx;
        if (n < N && k < K) tile[ty + r * 8][tx] = W[(size_t)n * K + k];
    }
    __syncthreads();
#pragma unroll
    for (int r = 0; r < 4; ++r) {
        int k = k0 + ty + r * 8, n = n0 + tx;
        if (k < K && n < N) WT[(size_t)k * N + n] = tile[tx][ty + r * 8];
    }
}

// Layer-1 sparse accumulate. One block per row r = t*256+b, t=0..97.
// Thread owns 4 CONTIGUOUS cols [tid*4, tid*4+4) -> all weight reads are
// global_load_dwordx4 (1 KB/wave) instead of dword (256 B/wave).
__global__ __launch_bounds__(256) void sparse1(const float* __restrict__ x,
                                               const float* __restrict__ W1T,
                                               float* __restrict__ C1) {
    __shared__ unsigned short list[800];
    __shared__ int cnt;
    const int tid = threadIdx.x;
    const int row = blockIdx.x;
    if (tid == 0) cnt = 0;
    __syncthreads();
    if (tid < 196) {   // 196 * 4 = 784 exactly
        const float4 v = *(const float4*)(x + (size_t)row * 784 + tid * 4);
        if (v.x != 0.0f) list[atomicAdd(&cnt, 1)] = (unsigned short)(tid * 4 + 0);
        if (v.y != 0.0f) list[atomicAdd(&cnt, 1)] = (unsigned short)(tid * 4 + 1);
        if (v.z != 0.0f) list[atomicAdd(&cnt, 1)] = (unsigned short)(tid * 4 + 2);
        if (v.w != 0.0f) list[atomicAdd(&cnt, 1)] = (unsigned short)(tid * 4 + 3);
    }
    __syncthreads();
    const int n = cnt;
    float4 acc = {0.0f, 0.0f, 0.0f, 0.0f};
    const float* base = W1T + tid * 4;
    int i = 0;
    for (; i + 4 <= n; i += 4) {   // 4-deep: 4 independent dwordx4 in flight
        float4 w0 = *(const float4*)(base + (size_t)list[i + 0] * 1024);
        float4 w1 = *(const float4*)(base + (size_t)list[i + 1] * 1024);
        float4 w2 = *(const float4*)(base + (size_t)list[i + 2] * 1024);
        float4 w3 = *(const float4*)(base + (size_t)list[i + 3] * 1024);
        acc.x += (w0.x + w1.x) + (w2.x + w3.x);
        acc.y += (w0.y + w1.y) + (w2.y + w3.y);
        acc.z += (w0.z + w1.z) + (w2.z + w3.z);
        acc.w += (w0.w + w1.w) + (w2.w + w3.w);
    }
    for (; i < n; ++i) {
        float4 w0 = *(const float4*)(base + (size_t)list[i] * 1024);
        acc.x += w0.x; acc.y += w0.y; acc.z += w0.z; acc.w += w0.w;
    }
    *(float4*)(C1 + (size_t)row * 1024 + tid * 4) = acc;
}

// Layer-1 scan: thread owns 4 contiguous (b,n) cols. C1 rows t=0..97.
// Writes S1 (uint8 spikes) rows t=0 (zeros) .. 98. Row stride 262144.
__global__ __launch_bounds__(256) void scan1(const float* __restrict__ C1,
                                             unsigned char* __restrict__ S1) {
    const int idx = blockIdx.x * 256 + threadIdx.x;   // 0..65535, *4 = col
    uchar4 z = {0, 0, 0, 0};
    *(uchar4*)(S1 + (size_t)idx * 4) = z;             // t = 0
    float4 I = {0, 0, 0, 0}, V = {0, 0, 0, 0};
    for (int t = 1; t <= 98; ++t) {
        float4 c = *(const float4*)(C1 + (size_t)(t - 1) * 262144 + (size_t)idx * 4);
        uchar4 s;
        I.x = ALPHA_F * I.x + c.x;
        I.y = ALPHA_F * I.y + c.y;
        I.z = ALPHA_F * I.z + c.z;
        I.w = ALPHA_F * I.w + c.w;
        float vx = BETA_F * V.x + ONE_MINUS_BETA_F * I.x;
        float vy = BETA_F * V.y + ONE_MINUS_BETA_F * I.y;
        float vz = BETA_F * V.z + ONE_MINUS_BETA_F * I.z;
        float vw = BETA_F * V.w + ONE_MINUS_BETA_F * I.w;
        s.x = vx > 1.0f; s.y = vy > 1.0f; s.z = vz > 1.0f; s.w = vw > 1.0f;
        V.x = s.x ? 0.0f : vx; V.y = s.y ? 0.0f : vy;
        V.z = s.z ? 0.0f : vz; V.w = s.w ? 0.0f : vw;
        *(uchar4*)(S1 + (size_t)t * 262144 + (size_t)idx * 4) = s;
    }
}

// Layer 2 fully fused: one 64-lane wave per batch b. Thread owns 4 contiguous
// output cols (4*64 = 256). Per t: read S1 row (16 B/lane = whole 1024-byte
// row), broadcast actives to all lanes via __ballot, gather W2T rows from
// L2-hot global (float4), then LIF scan in registers. Writes out directly.
__global__ __launch_bounds__(64) void layer2_fused(const unsigned char* __restrict__ S1,
                                                   const float* __restrict__ W2T,
                                                   float* __restrict__ out) {
    const int b = blockIdx.x;
    const int lane = threadIdx.x;
    float4 z = {0, 0, 0, 0};
    *(float4*)(out + (size_t)b * 256 + lane * 4) = z;  // t = 0 row
    float4 I = {0, 0, 0, 0}, V = {0, 0, 0, 0};

    const unsigned char* srow0 = S1 + (size_t)b * 1024;
    uint4 sv = *(const uint4*)(srow0 + lane * 16);     // row t-1 = 0
    for (int t = 1; t <= 99; ++t) {
        // prefetch next spike row while processing this one
        uint4 nv;
        if (t < 99)
            nv = *(const uint4*)(srow0 + (size_t)t * 262144 + lane * 16);
        // build 16-bit local active mask (bytes are 0/1)
        unsigned m16 = 0;
        m16 |= (sv.x & 0x000000FFu ? 1u : 0u) << 0;
        m16 |= (sv.x & 0x0000FF00u ? 1u : 0u) << 1;
        m16 |= (sv.x & 0x00FF0000u ? 1u : 0u) << 2;
        m16 |= (sv.x & 0xFF000000u ? 1u : 0u) << 3;
        m16 |= (sv.y & 0x000000FFu ? 1u : 0u) << 4;
        m16 |= (sv.y & 0x0000FF00u ? 1u : 0u) << 5;
        m16 |= (sv.y & 0x00FF0000u ? 1u : 0u) << 6;
        m16 |= (sv.y & 0xFF000000u ? 1u : 0u) << 7;
        m16 |= (sv.z & 0x000000FFu ? 1u : 0u) << 8;
        m16 |= (sv.z & 0x0000FF00u ? 1u : 0u) << 9;
        m16 |= (sv.z & 0x00FF0000u ? 1u : 0u) << 10;
        m16 |= (sv.z & 0xFF000000u ? 1u : 0u) << 11;
        m16 |= (sv.w & 0x000000FFu ? 1u : 0u) << 12;
        m16 |= (sv.w & 0x0000FF00u ? 1u : 0u) << 13;
        m16 |= (sv.w & 0x00FF0000u ? 1u : 0u) << 14;
        m16 |= (sv.w & 0xFF000000u ? 1u : 0u) << 15;

        float4 acc = {0, 0, 0, 0};
#pragma unroll 1
        for (int j = 0; j < 16; ++j) {
            unsigned long long bm = __ballot((m16 >> j) & 1u);
            while (bm) {
                int L = __ffsll(bm) - 1;
                bm &= bm - 1;
                int k = L * 16 + j;   // active presynaptic neuron
                float4 w = *(const float4*)(W2T + (size_t)k * 256 + lane * 4);
                acc.x += w.x; acc.y += w.y; acc.z += w.z; acc.w += w.w;
            }
        }
        I.x = ALPHA_F * I.x + acc.x;
        I.y = ALPHA_F * I.y + acc.y;
        I.z = ALPHA_F * I.z + acc.z;
        I.w = ALPHA_F * I.w + acc.w;
        float vx = BETA_F * V.x + ONE_MINUS_BETA_F * I.x;
        float vy = BETA_F * V.y + ONE_MINUS_BETA_F * I.y;
        float vz = BETA_F * V.z + ONE_MINUS_BETA_F * I.z;
        float vw = BETA_F * V.w + ONE_MINUS_BETA_F * I.w;
        float4 s;
        s.x = vx > 1.0f ? 1.0f : 0.0f;
        s.y = vy > 1.0f ? 1.0f : 0.0f;
        s.z = vz > 1.0f ? 1.0f : 0.0f;
        s.w = vw > 1.0f ? 1.0f : 0.0f;
        V.x = (1.0f - s.x) * vx; V.y = (1.0f - s.y) * vy;
        V.z = (1.0f - s.z) * vz; V.w = (1.0f - s.w) * vw;
        *(float4*)(out + (size_t)t * 65536 + (size_t)b * 256 + lane * 4) = s;
        sv = nv;
    }
}

extern "C" void kernel_launch(void* const* d_in, const int* in_sizes, int n_in,
                              void* d_out, int out_size, void* d_ws, size_t ws_size,
                              hipStream_t stream) {
    const float* x  = (const float*)d_in[0];   // [100,256,784] binary
    const float* W1 = (const float*)d_in[1];   // [1024,784]
    const float* W2 = (const float*)d_in[2];   // [256,1024]
    float* out = (float*)d_out;                // [100,256,256]

    // Workspace:
    //   C1   : 25088*1024*4 = 102,760,448 B
    //   S1u8 : 25344*1024   =  25,952,256 B
    //   W1T  : 784*1024*4   =   3,211,264 B
    //   W2T  : 1024*256*4   =   1,048,576 B   (~133 MB total)
    char* ws = (char*)d_ws;
    float* C1 = (float*)ws;
    unsigned char* S1 = (unsigned char*)(ws + (size_t)25088 * 1024 * 4);
    float* W1T = (float*)(ws + (size_t)25088 * 1024 * 4 + (size_t)25344 * 1024);
    float* W2T = W1T + (size_t)784 * 1024;

    transpose_nt<<<dim3(25, 32), 256, 0, stream>>>(W1, W1T, 1024, 784);
    transpose_nt<<<dim3(32, 8), 256, 0, stream>>>(W2, W2T, 256, 1024);

    sparse1<<<25088, 256, 0, stream>>>(x, W1T, C1);
    scan1<<<256, 256, 0, stream>>>(C1, S1);
    layer2_fused<<<256, 64, 0, stream>>>(S1, W2T, out);
}